// Round 18
// baseline (857.817 us; speedup 1.0000x reference)
//
#include <hip/hip_runtime.h>
#include <stdint.h>
#include <stddef.h>

// ---------- types ----------
typedef __bf16 bf16x8 __attribute__((ext_vector_type(8)));
typedef float  f32x4  __attribute__((ext_vector_type(4)));
typedef float  f32x2  __attribute__((ext_vector_type(2)));

// float -> bf16 bits, round-to-nearest-even (finite inputs)
__device__ __forceinline__ unsigned short f2bf(float f) {
  unsigned int u = __builtin_bit_cast(unsigned int, f);
  u += 0x7fffu + ((u >> 16) & 1u);
  return (unsigned short)(u >> 16);
}

__device__ __forceinline__ void gld_lds16(const void* g, void* l) {
  __builtin_amdgcn_global_load_lds(
      (__attribute__((address_space(1))) void*)(g),
      (__attribute__((address_space(3))) void*)(l), 16, 0, 0);
}

#define BAR()     asm volatile("s_barrier" ::: "memory")
#define WAITVM(n) asm volatile("s_waitcnt vmcnt(" #n ")" ::: "memory")
#define SCHED0()  __builtin_amdgcn_sched_barrier(0)

// ---------- kernel 1: quotient-remainder fake-quant of x, emit bf16 ----------
__global__ __launch_bounds__(256) void quant_x_kernel(
    const float* __restrict__ x, unsigned short* __restrict__ xb, long long ngroups)
{
  const int lane = threadIdx.x & 63;
  const int wv   = threadIdx.x >> 6;
  long long g = (long long)blockIdx.x * 4 + wv;
  if (g >= ngroups) return;

  const float* xg = x + g * 128;
  f32x2 v = __builtin_nontemporal_load(
      reinterpret_cast<const f32x2*>(xg + lane * 2));

  float m = fmaxf(fabsf(v[0]), fabsf(v[1]));
  #pragma unroll
  for (int off = 32; off; off >>= 1) m = fmaxf(m, __shfl_xor(m, off));
  m = fmaxf(m, 1e-8f);

  float t = m / 7.0f;
  float base = t <= 2.f ? 2.f : t <= 4.f ? 4.f : t <= 8.f ? 8.f
             : t <= 16.f ? 16.f : t <= 32.f ? 32.f : 64.f;
  float inv_base = 1.0f / base;

  float q0 = fminf(fmaxf(rintf(v[0] * inv_base), -7.f), 7.f);
  float q1 = fminf(fmaxf(rintf(v[1] * inv_base), -7.f), 7.f);
  float r0 = v[0] - base * q0;
  float r1 = v[1] - base * q1;

  float mr = fmaxf(fabsf(r0), fabsf(r1));
  #pragma unroll
  for (int off = 32; off; off >>= 1) mr = fmaxf(mr, __shfl_xor(mr, off));
  mr = fmaxf(mr, 1e-8f);
  float scale_r = mr / 7.0f;

  float rd0 = fminf(fmaxf(rintf(r0 / scale_r), -8.f), 7.f) * scale_r;
  float rd1 = fminf(fmaxf(rintf(r1 / scale_r), -8.f), 7.f) * scale_r;

  float y0 = base * q0 + rd0;
  float y1 = base * q1 + rd1;

  unsigned int packed = (unsigned int)f2bf(y0) | ((unsigned int)f2bf(y1) << 16);
  *reinterpret_cast<unsigned int*>(xb + g * 128 + lane * 2) = packed;
}

// ---------- kernel 2: fp32 -> bf16 weight conversion ----------
__global__ __launch_bounds__(256) void cvt_w_kernel(
    const float* __restrict__ w, unsigned short* __restrict__ wb, long long n)
{
  long long i = ((long long)blockIdx.x * blockDim.x + threadIdx.x) * 8;
  if (i + 7 >= n) {
    if (i >= n) return;
    for (long long j = i; j < n; ++j) wb[j] = f2bf(w[j]);
    return;
  }
  f32x4 v0 = __builtin_nontemporal_load(reinterpret_cast<const f32x4*>(w + i));
  f32x4 v1 = __builtin_nontemporal_load(reinterpret_cast<const f32x4*>(w + i + 4));
  uint4 o;
  o.x = (unsigned)f2bf(v0[0]) | ((unsigned)f2bf(v0[1]) << 16);
  o.y = (unsigned)f2bf(v0[2]) | ((unsigned)f2bf(v0[3]) << 16);
  o.z = (unsigned)f2bf(v1[0]) | ((unsigned)f2bf(v1[1]) << 16);
  o.w = (unsigned)f2bf(v1[2]) | ((unsigned)f2bf(v1[3]) << 16);
  *reinterpret_cast<uint4*>(wb + i) = o;
}

// ---------- kernel 3: 128x256-tile, BK=32, 2-BLOCKS-PER-CU GEMM + bias -------
// R14's intended experiment done RIGHT.  Block = 128x256, 8 waves in a 2x4
// grid of 64x64 wave-tiles (acc[4][4] -- every output row covered exactly
// once; re-derived and chunk-checked).  BK=32 -> LDS = 2dbuf x (A 8KB +
// B 16KB) = 48 KiB -> TWO independent blocks per CU; __launch_bounds__(512,4)
// caps VGPR at 128 (tally ~116).  Mechanism (m114): independent blocks'
// barrier/vmcnt/staging bubbles are filled by the co-resident block's MFMAs
// -- the cross-CU-convoy breaker no single-block schedule achieved (R4-R16
// all 43-49% MfmaUtil).  Schedule per K-tile (R10 structure): stage(t+1 ->
// other dbuf) ; 8 ds_reads ; SCHED0 ; 16 MFMA ; vmcnt(0) ; BAR.
// Swizzle: read slot = laneh ^ (laneq&3); staged chunk c holds row c>>2,
// gslot (c&3)^((c>>2)&3)  [verified: lane gets k=laneh*8 exactly].
#define BM 128
#define BN 256
#define BK 32

#define MFMA16(a, b, c) __builtin_amdgcn_mfma_f32_16x16x32_bf16(a, b, c, 0, 0, 0)

__global__ __launch_bounds__(512, 4) void gemm256_bias(
    const unsigned short* __restrict__ A,   // [M][K] bf16 bits
    const unsigned short* __restrict__ B,   // [N][K] bf16 bits
    const float* __restrict__ bias,         // [N]
    float* __restrict__ C,                  // [M][N] fp32
    int M, int N, int K)
{
  // [dbuf][ A 128x32 (8KB) | B 256x32 (16KB) ] = 48 KiB total
  __shared__ unsigned short lds[2][12288];

  const int tid  = threadIdx.x;
  const int lane = tid & 63;
  const int wid  = tid >> 6;       // 0..7
  const int wm   = wid >> 2;       // 0..1  (64-row band of A)
  const int wn   = wid & 3;        // 0..3  (64-col band of B)
  const int laneq = lane & 15;
  const int laneh = lane >> 4;     // 0..3 -> k = laneh*8

  // ---- supertile remap (L3) + XCD-compact sub-map (L2) ----
  const int ntm = M / BM;          // 64
  const int ntn = N / BN;          // 43
  int tm, tn;
  if ((ntm & 15) == 0) {
    int rem = blockIdx.x;
    int str = 0, stc = 0, w = 16;
    for (;;) {
      int w2 = (ntn - stc * 16 < 16) ? (ntn - stc * 16) : 16;
      int sz = 16 * w2;
      if (rem < sz) { w = w2; break; }
      rem -= sz;
      ++stc;
      if (stc * 16 >= ntn) { stc = 0; ++str; }
    }
    if (w == 16) {
      int x = rem & 7, q = rem >> 3;
      tm = str * 16 + 2 * (q & 7) + (x & 1);
      tn = stc * 16 + 4 * (q >> 3) + (x >> 1);
    } else {
      tm = str * 16 + rem / w;
      tn = stc * 16 + rem % w;
    }
  } else {
    tm = (int)blockIdx.x / ntn;
    tn = (int)blockIdx.x % ntn;
  }
  const size_t m0 = (size_t)tm * BM;
  const size_t n0 = (size_t)tn * BN;

  const int NT = K / BK;           // 128

  // ---- reader addressing: row stride 64B, slot = laneh ^ (laneq&3) ----
  const int slotR = laneh ^ (laneq & 3);
  const char* ldsb = (const char*)&lds[0][0];
  const int aOff = (wm * 64 + laneq) * 64 + slotR * 16;            // A region
  const int bOff = 8192 + (wn * 64 + laneq) * 64 + slotR * 16;     // B region

  // ---- staging source pointers (computed once) ----
  // chunk c: row c>>2, gslot (c&3)^((c>>2)&3).  load0: A chunk tid;
  // load1: B chunk tid; load2: B chunk tid+512 (row +128, same gslot).
  const int rS = tid >> 2;                         // 0..127
  const int gs = (tid & 3) ^ (rS & 3);
  const unsigned short* gA0 = A + (m0 + rS) * (size_t)K + gs * 8;
  const unsigned short* gB0 = B + (n0 + rS) * (size_t)K + gs * 8;
  const unsigned short* gB1 = B + (n0 + rS + 128) * (size_t)K + gs * 8;

  char* dstT = (char*)ldsb + tid * 16;   // dbuf0; dbuf1 = +24576

  f32x4 acc[4][4];
  #pragma unroll
  for (int i = 0; i < 4; i++)
    #pragma unroll
    for (int j = 0; j < 4; j++)
      acc[i][j] = (f32x4){0.f, 0.f, 0.f, 0.f};

  // stage one full 128x32 A + 256x32 B K-tile: 3 gld_lds16 / thread
  #define STAGETILE(kt, dstD)                                                \
    do {                                                                     \
      gld_lds16(gA0 + (size_t)(kt) * 32, (dstD));                            \
      gld_lds16(gB0 + (size_t)(kt) * 32, (dstD) + 8192);                     \
      gld_lds16(gB1 + (size_t)(kt) * 32, (dstD) + 16384);                    \
    } while (0)

  // ---- prologue: stage tile0 into dbuf0 ----
  STAGETILE(0, dstT);
  WAITVM(0);
  BAR();

  bf16x8 af[4], bf[4];

  for (int t = 0; t < NT; ++t) {
    const int d = t & 1;
    const char* aB = ldsb + d * 24576 + aOff;
    const char* bB = ldsb + d * 24576 + bOff;

    // ---- stage tile t+1 into the other buffer (dead since last BAR) ----
    if (t + 1 < NT) STAGETILE(t + 1, dstT + (d ^ 1) * 24576);

    // ---- 8 ds_read_b128, then 16 independent MFMA ----
    #pragma unroll
    for (int mi = 0; mi < 4; ++mi)
      af[mi] = *(const bf16x8*)(aB + mi * 1024);
    #pragma unroll
    for (int nj = 0; nj < 4; ++nj)
      bf[nj] = *(const bf16x8*)(bB + nj * 1024);
    SCHED0();   // fence: reads stay above, MFMAs stay below

    __builtin_amdgcn_s_setprio(1);
    #pragma unroll
    for (int mi = 0; mi < 4; ++mi)
      #pragma unroll
      for (int nj = 0; nj < 4; ++nj)
        acc[mi][nj] = MFMA16(af[mi], bf[nj], acc[mi][nj]);
    __builtin_amdgcn_s_setprio(0);

    // tile t+1's staging (issued a full tile-body ago) must land before
    // the next iteration's reads
    WAITVM(0);
    BAR();
  }
  #undef STAGETILE

  // ---- epilogue: C = acc + bias (non-temporal: don't churn L3) ----
  // C/D layout: col = lane&15, row = (lane>>4)*4 + reg
  #pragma unroll
  for (int nj = 0; nj < 4; ++nj) {
    int col = (int)n0 + wn * 64 + nj * 16 + laneq;
    float bv = bias[col];
    #pragma unroll
    for (int mi = 0; mi < 4; ++mi) {
      size_t row = m0 + wm * 64 + mi * 16 + laneh * 4;
      float* cp = C + row * (size_t)N + col;
      #pragma unroll
      for (int r = 0; r < 4; ++r)
        __builtin_nontemporal_store(acc[mi][nj][r] + bv, cp + (size_t)r * N);
    }
  }
}

// ---------- launcher ----------
extern "C" void kernel_launch(void* const* d_in, const int* in_sizes, int n_in,
                              void* d_out, int out_size, void* d_ws, size_t ws_size,
                              hipStream_t stream) {
  const float* x    = (const float*)d_in[0];
  const float* w    = (const float*)d_in[1];
  const float* bias = (const float*)d_in[2];
  float* out = (float*)d_out;

  const long long xN = in_sizes[0];          // M*K
  const long long wN = in_sizes[1];          // N*K
  const int N = in_sizes[2];
  const int K = (int)(wN / N);
  const int M = (int)(xN / K);

  unsigned short* xb = (unsigned short*)d_ws;          // M*K bf16
  unsigned short* wb = xb + xN;                        // N*K bf16

  long long ngroups = xN / 128;
  long long qblocks = (ngroups + 3) / 4;
  quant_x_kernel<<<(int)qblocks, 256, 0, stream>>>(x, xb, ngroups);

  long long cblocks = (wN + 2047) / 2048;
  cvt_w_kernel<<<(int)cblocks, 256, 0, stream>>>(w, wb, wN);

  int grid = (M / BM) * (N / BN);
  gemm256_bias<<<grid, 512, 0, stream>>>(xb, wb, bias, out, M, N, K);
}

// Round 19
// 855.371 us; speedup vs baseline: 1.0029x; 1.0029x over previous
//
#include <hip/hip_runtime.h>
#include <stdint.h>
#include <stddef.h>

// ---------- types ----------
typedef __bf16 bf16x8 __attribute__((ext_vector_type(8)));
typedef float  f32x4  __attribute__((ext_vector_type(4)));
typedef float  f32x2  __attribute__((ext_vector_type(2)));

// float -> bf16 bits, round-to-nearest-even (finite inputs)
__device__ __forceinline__ unsigned short f2bf(float f) {
  unsigned int u = __builtin_bit_cast(unsigned int, f);
  u += 0x7fffu + ((u >> 16) & 1u);
  return (unsigned short)(u >> 16);
}

__device__ __forceinline__ void gld_lds16(const void* g, void* l) {
  __builtin_amdgcn_global_load_lds(
      (__attribute__((address_space(1))) void*)(g),
      (__attribute__((address_space(3))) void*)(l), 16, 0, 0);
}

#define BAR()     asm volatile("s_barrier" ::: "memory")
#define WAITVM(n) asm volatile("s_waitcnt vmcnt(" #n ")" ::: "memory")
#define SCHED0()  __builtin_amdgcn_sched_barrier(0)

// ---------- kernel 1: quotient-remainder fake-quant of x, emit bf16 ----------
__global__ __launch_bounds__(256) void quant_x_kernel(
    const float* __restrict__ x, unsigned short* __restrict__ xb, long long ngroups)
{
  const int lane = threadIdx.x & 63;
  const int wv   = threadIdx.x >> 6;
  long long g = (long long)blockIdx.x * 4 + wv;
  if (g >= ngroups) return;

  const float* xg = x + g * 128;
  f32x2 v = __builtin_nontemporal_load(
      reinterpret_cast<const f32x2*>(xg + lane * 2));

  float m = fmaxf(fabsf(v[0]), fabsf(v[1]));
  #pragma unroll
  for (int off = 32; off; off >>= 1) m = fmaxf(m, __shfl_xor(m, off));
  m = fmaxf(m, 1e-8f);

  float t = m / 7.0f;
  float base = t <= 2.f ? 2.f : t <= 4.f ? 4.f : t <= 8.f ? 8.f
             : t <= 16.f ? 16.f : t <= 32.f ? 32.f : 64.f;
  float inv_base = 1.0f / base;

  float q0 = fminf(fmaxf(rintf(v[0] * inv_base), -7.f), 7.f);
  float q1 = fminf(fmaxf(rintf(v[1] * inv_base), -7.f), 7.f);
  float r0 = v[0] - base * q0;
  float r1 = v[1] - base * q1;

  float mr = fmaxf(fabsf(r0), fabsf(r1));
  #pragma unroll
  for (int off = 32; off; off >>= 1) mr = fmaxf(mr, __shfl_xor(mr, off));
  mr = fmaxf(mr, 1e-8f);
  float scale_r = mr / 7.0f;

  float rd0 = fminf(fmaxf(rintf(r0 / scale_r), -8.f), 7.f) * scale_r;
  float rd1 = fminf(fmaxf(rintf(r1 / scale_r), -8.f), 7.f) * scale_r;

  float y0 = base * q0 + rd0;
  float y1 = base * q1 + rd1;

  unsigned int packed = (unsigned int)f2bf(y0) | ((unsigned int)f2bf(y1) << 16);
  *reinterpret_cast<unsigned int*>(xb + g * 128 + lane * 2) = packed;
}

// ---------- kernel 2: fp32 -> bf16 weight conversion ----------
__global__ __launch_bounds__(256) void cvt_w_kernel(
    const float* __restrict__ w, unsigned short* __restrict__ wb, long long n)
{
  long long i = ((long long)blockIdx.x * blockDim.x + threadIdx.x) * 8;
  if (i + 7 >= n) {
    if (i >= n) return;
    for (long long j = i; j < n; ++j) wb[j] = f2bf(w[j]);
    return;
  }
  f32x4 v0 = __builtin_nontemporal_load(reinterpret_cast<const f32x4*>(w + i));
  f32x4 v1 = __builtin_nontemporal_load(reinterpret_cast<const f32x4*>(w + i + 4));
  uint4 o;
  o.x = (unsigned)f2bf(v0[0]) | ((unsigned)f2bf(v0[1]) << 16);
  o.y = (unsigned)f2bf(v0[2]) | ((unsigned)f2bf(v0[3]) << 16);
  o.z = (unsigned)f2bf(v1[0]) | ((unsigned)f2bf(v1[1]) << 16);
  o.w = (unsigned)f2bf(v1[2]) | ((unsigned)f2bf(v1[3]) << 16);
  *reinterpret_cast<uint4*>(wb + i) = o;
}

// ---------- kernel 3: 128x256-tile, BK=32, 2-BLOCKS-PER-CU GEMM + bias -------
// R18 with the bank-conflict FIX.  R18's 9.0e7 conflicts: with 64B row
// stride, row's bank base = 16*(row&1); slot = laneh^(laneq&3) made lanes
// {x,x+4,x+8,x+12} (same parity+slot) collide 4-way.  FIX: slot =
// laneh ^ ((laneq>>1)&3) -> same-slot lanes {2k,2k+8} / {2k+1,2k+9} split
// across bank bases 0/16 -> max 2-way aliasing (free, m136).
// (row>>1)&3 is invariant under row+=16 (mi offsets) and row+=128 (staging
// pointer hoist); stored gslot (tid&3)^((tid>>3)&3) hands lane k=laneh*8
// exactly (derivation re-checked).  All else = R18: 8 waves in 2x4 grid of
// 64x64 wave-tiles, 48 KiB LDS -> 2 blocks/CU, one-barrier counted schedule,
// supertile+XCD remap, nt stores.
#define BM 128
#define BN 256
#define BK 32

#define MFMA16(a, b, c) __builtin_amdgcn_mfma_f32_16x16x32_bf16(a, b, c, 0, 0, 0)

__global__ __launch_bounds__(512, 4) void gemm256_bias(
    const unsigned short* __restrict__ A,   // [M][K] bf16 bits
    const unsigned short* __restrict__ B,   // [N][K] bf16 bits
    const float* __restrict__ bias,         // [N]
    float* __restrict__ C,                  // [M][N] fp32
    int M, int N, int K)
{
  // [dbuf][ A 128x32 (8KB) | B 256x32 (16KB) ] = 48 KiB total
  __shared__ unsigned short lds[2][12288];

  const int tid  = threadIdx.x;
  const int lane = tid & 63;
  const int wid  = tid >> 6;       // 0..7
  const int wm   = wid >> 2;       // 0..1  (64-row band of A)
  const int wn   = wid & 3;        // 0..3  (64-col band of B)
  const int laneq = lane & 15;
  const int laneh = lane >> 4;     // 0..3 -> k = laneh*8

  // ---- supertile remap (L3) + XCD-compact sub-map (L2) ----
  const int ntm = M / BM;          // 64
  const int ntn = N / BN;          // 43
  int tm, tn;
  if ((ntm & 15) == 0) {
    int rem = blockIdx.x;
    int str = 0, stc = 0, w = 16;
    for (;;) {
      int w2 = (ntn - stc * 16 < 16) ? (ntn - stc * 16) : 16;
      int sz = 16 * w2;
      if (rem < sz) { w = w2; break; }
      rem -= sz;
      ++stc;
      if (stc * 16 >= ntn) { stc = 0; ++str; }
    }
    if (w == 16) {
      int x = rem & 7, q = rem >> 3;
      tm = str * 16 + 2 * (q & 7) + (x & 1);
      tn = stc * 16 + 4 * (q >> 3) + (x >> 1);
    } else {
      tm = str * 16 + rem / w;
      tn = stc * 16 + rem % w;
    }
  } else {
    tm = (int)blockIdx.x / ntn;
    tn = (int)blockIdx.x % ntn;
  }
  const size_t m0 = (size_t)tm * BM;
  const size_t n0 = (size_t)tn * BN;

  const int NT = K / BK;           // 128

  // ---- reader addressing: row stride 64B, slot = laneh ^ ((laneq>>1)&3) ----
  const int slotR = laneh ^ ((laneq >> 1) & 3);
  const char* ldsb = (const char*)&lds[0][0];
  const int aOff = (wm * 64 + laneq) * 64 + slotR * 16;            // A region
  const int bOff = 8192 + (wn * 64 + laneq) * 64 + slotR * 16;     // B region

  // ---- staging source pointers (computed once) ----
  // chunk c: row c>>2, lslot c&3, gslot = (c&3) ^ ((c>>3)&3)  [(row>>1)&3].
  // load0: A chunk tid; load1: B chunk tid; load2: B chunk tid+512
  // (row +128 -> (row>>1)&3 unchanged -> same gslot, pointer hoists).
  const int rS = tid >> 2;                         // 0..127
  const int gs = (tid & 3) ^ ((tid >> 3) & 3);
  const unsigned short* gA0 = A + (m0 + rS) * (size_t)K + gs * 8;
  const unsigned short* gB0 = B + (n0 + rS) * (size_t)K + gs * 8;
  const unsigned short* gB1 = B + (n0 + rS + 128) * (size_t)K + gs * 8;

  char* dstT = (char*)ldsb + tid * 16;   // dbuf0; dbuf1 = +24576

  f32x4 acc[4][4];
  #pragma unroll
  for (int i = 0; i < 4; i++)
    #pragma unroll
    for (int j = 0; j < 4; j++)
      acc[i][j] = (f32x4){0.f, 0.f, 0.f, 0.f};

  // stage one full 128x32 A + 256x32 B K-tile: 3 gld_lds16 / thread
  #define STAGETILE(kt, dstD)                                                \
    do {                                                                     \
      gld_lds16(gA0 + (size_t)(kt) * 32, (dstD));                            \
      gld_lds16(gB0 + (size_t)(kt) * 32, (dstD) + 8192);                     \
      gld_lds16(gB1 + (size_t)(kt) * 32, (dstD) + 16384);                    \
    } while (0)

  // ---- prologue: stage tile0 into dbuf0 ----
  STAGETILE(0, dstT);
  WAITVM(0);
  BAR();

  bf16x8 af[4], bf[4];

  for (int t = 0; t < NT; ++t) {
    const int d = t & 1;
    const char* aB = ldsb + d * 24576 + aOff;
    const char* bB = ldsb + d * 24576 + bOff;

    // ---- stage tile t+1 into the other buffer (dead since last BAR) ----
    if (t + 1 < NT) STAGETILE(t + 1, dstT + (d ^ 1) * 24576);

    // ---- 8 ds_read_b128, then 16 independent MFMA ----
    #pragma unroll
    for (int mi = 0; mi < 4; ++mi)
      af[mi] = *(const bf16x8*)(aB + mi * 1024);
    #pragma unroll
    for (int nj = 0; nj < 4; ++nj)
      bf[nj] = *(const bf16x8*)(bB + nj * 1024);
    SCHED0();   // fence: reads stay above, MFMAs stay below

    __builtin_amdgcn_s_setprio(1);
    #pragma unroll
    for (int mi = 0; mi < 4; ++mi)
      #pragma unroll
      for (int nj = 0; nj < 4; ++nj)
        acc[mi][nj] = MFMA16(af[mi], bf[nj], acc[mi][nj]);
    __builtin_amdgcn_s_setprio(0);

    // tile t+1's staging (issued a full tile-body ago) must land before
    // the next iteration's reads
    WAITVM(0);
    BAR();
  }
  #undef STAGETILE

  // ---- epilogue: C = acc + bias (non-temporal: don't churn L3) ----
  // C/D layout: col = lane&15, row = (lane>>4)*4 + reg
  #pragma unroll
  for (int nj = 0; nj < 4; ++nj) {
    int col = (int)n0 + wn * 64 + nj * 16 + laneq;
    float bv = bias[col];
    #pragma unroll
    for (int mi = 0; mi < 4; ++mi) {
      size_t row = m0 + wm * 64 + mi * 16 + laneh * 4;
      float* cp = C + row * (size_t)N + col;
      #pragma unroll
      for (int r = 0; r < 4; ++r)
        __builtin_nontemporal_store(acc[mi][nj][r] + bv, cp + (size_t)r * N);
    }
  }
}

// ---------- launcher ----------
extern "C" void kernel_launch(void* const* d_in, const int* in_sizes, int n_in,
                              void* d_out, int out_size, void* d_ws, size_t ws_size,
                              hipStream_t stream) {
  const float* x    = (const float*)d_in[0];
  const float* w    = (const float*)d_in[1];
  const float* bias = (const float*)d_in[2];
  float* out = (float*)d_out;

  const long long xN = in_sizes[0];          // M*K
  const long long wN = in_sizes[1];          // N*K
  const int N = in_sizes[2];
  const int K = (int)(wN / N);
  const int M = (int)(xN / K);

  unsigned short* xb = (unsigned short*)d_ws;          // M*K bf16
  unsigned short* wb = xb + xN;                        // N*K bf16

  long long ngroups = xN / 128;
  long long qblocks = (ngroups + 3) / 4;
  quant_x_kernel<<<(int)qblocks, 256, 0, stream>>>(x, xb, ngroups);

  long long cblocks = (wN + 2047) / 2048;
  cvt_w_kernel<<<(int)cblocks, 256, 0, stream>>>(w, wb, wN);

  int grid = (M / BM) * (N / BN);
  gemm256_bias<<<grid, 512, 0, stream>>>(xb, wb, bias, out, M, N, K);
}

// Round 20
// 753.921 us; speedup vs baseline: 1.1378x; 1.1346x over previous
//
#include <hip/hip_runtime.h>
#include <stdint.h>
#include <stddef.h>

// ---------- types ----------
typedef __bf16 bf16x8 __attribute__((ext_vector_type(8)));
typedef float  f32x4  __attribute__((ext_vector_type(4)));
typedef float  f32x2  __attribute__((ext_vector_type(2)));

// float -> bf16 bits, round-to-nearest-even (finite inputs)
__device__ __forceinline__ unsigned short f2bf(float f) {
  unsigned int u = __builtin_bit_cast(unsigned int, f);
  u += 0x7fffu + ((u >> 16) & 1u);
  return (unsigned short)(u >> 16);
}

__device__ __forceinline__ void gld_lds16(const void* g, void* l) {
  __builtin_amdgcn_global_load_lds(
      (__attribute__((address_space(1))) void*)(g),
      (__attribute__((address_space(3))) void*)(l), 16, 0, 0);
}

#define BAR()     asm volatile("s_barrier" ::: "memory")
#define WAITVM(n) asm volatile("s_waitcnt vmcnt(" #n ")" ::: "memory")
#define SCHED0()  __builtin_amdgcn_sched_barrier(0)

// ---------- kernel 1: quotient-remainder fake-quant of x, emit bf16 ----------
__global__ __launch_bounds__(256) void quant_x_kernel(
    const float* __restrict__ x, unsigned short* __restrict__ xb, long long ngroups)
{
  const int lane = threadIdx.x & 63;
  const int wv   = threadIdx.x >> 6;
  long long g = (long long)blockIdx.x * 4 + wv;
  if (g >= ngroups) return;

  const float* xg = x + g * 128;
  f32x2 v = __builtin_nontemporal_load(
      reinterpret_cast<const f32x2*>(xg + lane * 2));

  float m = fmaxf(fabsf(v[0]), fabsf(v[1]));
  #pragma unroll
  for (int off = 32; off; off >>= 1) m = fmaxf(m, __shfl_xor(m, off));
  m = fmaxf(m, 1e-8f);

  float t = m / 7.0f;
  float base = t <= 2.f ? 2.f : t <= 4.f ? 4.f : t <= 8.f ? 8.f
             : t <= 16.f ? 16.f : t <= 32.f ? 32.f : 64.f;
  float inv_base = 1.0f / base;

  float q0 = fminf(fmaxf(rintf(v[0] * inv_base), -7.f), 7.f);
  float q1 = fminf(fmaxf(rintf(v[1] * inv_base), -7.f), 7.f);
  float r0 = v[0] - base * q0;
  float r1 = v[1] - base * q1;

  float mr = fmaxf(fabsf(r0), fabsf(r1));
  #pragma unroll
  for (int off = 32; off; off >>= 1) mr = fmaxf(mr, __shfl_xor(mr, off));
  mr = fmaxf(mr, 1e-8f);
  float scale_r = mr / 7.0f;

  float rd0 = fminf(fmaxf(rintf(r0 / scale_r), -8.f), 7.f) * scale_r;
  float rd1 = fminf(fmaxf(rintf(r1 / scale_r), -8.f), 7.f) * scale_r;

  float y0 = base * q0 + rd0;
  float y1 = base * q1 + rd1;

  unsigned int packed = (unsigned int)f2bf(y0) | ((unsigned int)f2bf(y1) << 16);
  *reinterpret_cast<unsigned int*>(xb + g * 128 + lane * 2) = packed;
}

// ---------- kernel 2: fp32 -> bf16 weight conversion ----------
__global__ __launch_bounds__(256) void cvt_w_kernel(
    const float* __restrict__ w, unsigned short* __restrict__ wb, long long n)
{
  long long i = ((long long)blockIdx.x * blockDim.x + threadIdx.x) * 8;
  if (i + 7 >= n) {
    if (i >= n) return;
    for (long long j = i; j < n; ++j) wb[j] = f2bf(w[j]);
    return;
  }
  f32x4 v0 = __builtin_nontemporal_load(reinterpret_cast<const f32x4*>(w + i));
  f32x4 v1 = __builtin_nontemporal_load(reinterpret_cast<const f32x4*>(w + i + 4));
  uint4 o;
  o.x = (unsigned)f2bf(v0[0]) | ((unsigned)f2bf(v0[1]) << 16);
  o.y = (unsigned)f2bf(v0[2]) | ((unsigned)f2bf(v0[3]) << 16);
  o.z = (unsigned)f2bf(v1[0]) | ((unsigned)f2bf(v1[1]) << 16);
  o.w = (unsigned)f2bf(v1[2]) | ((unsigned)f2bf(v1[3]) << 16);
  *reinterpret_cast<uint4*>(wb + i) = o;
}

// ---------- kernel 3: 256x256-tile ONE-BARRIER counted-lgkm GEMM + bias ------
// FINAL (best verified, R15/R17: total 755 us, GEMM ~720 us ~= 1025 TF):
// R10 one-barrier schedule (stage t+1 -> dead buffer; all 24 ds_reads up
// front; counted-lgkm MFMA quadrants; one vmcnt(0)+BAR per K-tile — the
// vmcnt only waits on loads issued a full tile-body ago) + supertile remap
// (L3) + XCD-compact sub-map (L2) + nt C stores.
// Session ledger (R4-R19): T2 swizzle, 8-phase/counted-vmcnt, deep prefetch,
// reg-pipelining, barrier relaxation, one-barrier counted-lgkm, 32x32 MFMA
// (x2), fragment-order LDS, unit-aligned fine 8-phase, 2-blocks/CU (x2) —
// all converge to 43-49% MfmaUtil or regress; this structure is the max.
#define BM 256
#define BN 256
#define BK 64

#define MFMA16(a, b, c) __builtin_amdgcn_mfma_f32_16x16x32_bf16(a, b, c, 0, 0, 0)

__global__ __launch_bounds__(512, 2) void gemm256_bias(
    const unsigned short* __restrict__ A,   // [M][K] bf16 bits
    const unsigned short* __restrict__ B,   // [N][K] bf16 bits
    const float* __restrict__ bias,         // [N]
    float* __restrict__ C,                  // [M][N] fp32
    int M, int N, int K)
{
  __shared__ unsigned short lds[2][2][2][128 * 64];   // [dbuf][A/B][half] : 128 KiB

  const int tid  = threadIdx.x;
  const int lane = tid & 63;
  const int wid  = tid >> 6;       // 0..7
  const int wm   = wid >> 2;       // 0..1
  const int wn   = wid & 3;        // 0..3
  const int laneq = lane & 15;
  const int laneh = lane >> 4;
  const int lq7   = laneq & 7;

  // ---- supertile remap (L3 locality) + XCD-aware sub-map (L2 locality) ----
  const int ntm = M / BM;
  const int ntn = N / BN;
  int tm, tn;
  if ((ntm & 15) == 0) {
    int rem = blockIdx.x;
    int str = 0, stc = 0, w = 16;
    for (;;) {
      int w2 = (ntn - stc * 16 < 16) ? (ntn - stc * 16) : 16;
      int sz = 16 * w2;
      if (rem < sz) { w = w2; break; }
      rem -= sz;
      ++stc;
      if (stc * 16 >= ntn) { stc = 0; ++str; }
    }
    if (w == 16) {
      // XCD-compact: same (rem%8) -> 8 rows (fixed parity) x 4 cols
      int x = rem & 7, q = rem >> 3;
      tm = str * 16 + 2 * (q & 7) + (x & 1);
      tn = stc * 16 + 4 * (q >> 3) + (x >> 1);
    } else {
      tm = str * 16 + rem / w;
      tn = stc * 16 + rem % w;
    }
  } else {
    tm = (int)blockIdx.x / ntn;
    tn = (int)blockIdx.x % ntn;
  }
  const size_t m0 = (size_t)tm * BM;
  const size_t n0 = (size_t)tn * BN;

  const int NT = K / BK;

  // swizzled 16B-slot indices for ks=0,1
  const int ss0 = (laneh ^ lq7);        // slot 0..7
  const int ss1 = ((4 + laneh) ^ lq7);

  // per-thread LDS read base offsets (bytes)
  const char* ldsb = (const char*)&lds[0][0][0][0];
  const int aOff = wm * 16384 + laneq * 128;
  const int bOff = 32768 + (wn >> 1) * 16384 + ((wn & 1) * 64 + laneq) * 128;

  // per-thread staging source pointers (computed once)
  const int c0 = tid, c1 = 512 + tid;
  const int r0 = c0 >> 3, sl0 = (c0 & 7) ^ (r0 & 7);
  const int r1 = c1 >> 3, sl1 = (c1 & 7) ^ (r1 & 7);
  const unsigned short* gA0 = A + (m0 + r0) * (size_t)K + sl0 * 8;
  const unsigned short* gA1 = A + (m0 + r1) * (size_t)K + sl1 * 8;
  const unsigned short* gB0 = B + (n0 + r0) * (size_t)K + sl0 * 8;
  const unsigned short* gB1 = B + (n0 + r1) * (size_t)K + sl1 * 8;
  const size_t hstep = (size_t)128 * K;   // +128 rows

  // per-thread staging LDS dest bases (bytes)
  char* dst0 = (char*)ldsb + wid * 1024;           // dbuf 0
  char* dst1 = dst0 + 65536;                       // dbuf 1

  f32x4 acc[8][4];
  #pragma unroll
  for (int i = 0; i < 8; i++)
    #pragma unroll
    for (int j = 0; j < 4; j++)
      acc[i][j] = (f32x4){0.f, 0.f, 0.f, 0.f};

  // stage one full 256x64 K-tile (A+B, both halves): 8 gld_lds16 / thread
  #define STAGETILE(kt, dstD)                                                \
    do {                                                                     \
      gld_lds16(gA0 + (size_t)(kt) * 64,          (dstD));                   \
      gld_lds16(gA1 + (size_t)(kt) * 64,          (dstD) + 8192);            \
      gld_lds16(gA0 + hstep + (size_t)(kt) * 64,  (dstD) + 16384);           \
      gld_lds16(gA1 + hstep + (size_t)(kt) * 64,  (dstD) + 16384 + 8192);    \
      gld_lds16(gB0 + (size_t)(kt) * 64,          (dstD) + 32768);           \
      gld_lds16(gB1 + (size_t)(kt) * 64,          (dstD) + 32768 + 8192);    \
      gld_lds16(gB0 + hstep + (size_t)(kt) * 64,  (dstD) + 49152);           \
      gld_lds16(gB1 + hstep + (size_t)(kt) * 64,  (dstD) + 49152 + 8192);    \
    } while (0)

  // ---- prologue: stage tile0 into dbuf0 ----
  STAGETILE(0, dst0);
  WAITVM(0);
  BAR();

  bf16x8 al[4][2], ah[4][2], bl[2][2], bh[2][2];

  for (int t = 0; t < NT; ++t) {
    const int d = t & 1;
    const char* aS0 = ldsb + (d << 16) + aOff + ss0 * 16;
    const char* aS1 = ldsb + (d << 16) + aOff + ss1 * 16;
    const char* bS0 = ldsb + (d << 16) + bOff + ss0 * 16;
    const char* bS1 = ldsb + (d << 16) + bOff + ss1 * 16;

    // ---- stage tile t+1 into the other buffer (dead since last BAR) ----
    if (t + 1 < NT) { char* dn = d ? dst0 : dst1; STAGETILE(t + 1, dn); }

    // ---- issue ALL 24 ds_reads up front: al(8), bl(4), bh(4), ah(8) ----
    #pragma unroll
    for (int mi = 0; mi < 4; ++mi) {
      al[mi][0] = *(const bf16x8*)(aS0 + mi * 2048);
      al[mi][1] = *(const bf16x8*)(aS1 + mi * 2048);
    }
    #pragma unroll
    for (int nj = 0; nj < 2; ++nj) {
      bl[nj][0] = *(const bf16x8*)(bS0 + nj * 2048);
      bl[nj][1] = *(const bf16x8*)(bS1 + nj * 2048);
    }
    #pragma unroll
    for (int nj = 0; nj < 2; ++nj) {
      bh[nj][0] = *(const bf16x8*)(bS0 + 4096 + nj * 2048);
      bh[nj][1] = *(const bf16x8*)(bS1 + 4096 + nj * 2048);
    }
    #pragma unroll
    for (int mi = 0; mi < 4; ++mi) {
      ah[mi][0] = *(const bf16x8*)(aS0 + 8192 + mi * 2048);
      ah[mi][1] = *(const bf16x8*)(aS1 + 8192 + mi * 2048);
    }
    SCHED0();   // fence: reads stay above, MFMAs stay below

    __builtin_amdgcn_s_setprio(1);
    // Q1: al x bl  (waits lgkm for al/bl only; bh/ah serviced during MFMA)
    #pragma unroll
    for (int mi = 0; mi < 4; ++mi)
      #pragma unroll
      for (int nj = 0; nj < 2; ++nj) {
        acc[mi][nj] = MFMA16(al[mi][0], bl[nj][0], acc[mi][nj]);
        acc[mi][nj] = MFMA16(al[mi][1], bl[nj][1], acc[mi][nj]);
      }
    SCHED0();
    // Q2: al x bh
    #pragma unroll
    for (int mi = 0; mi < 4; ++mi)
      #pragma unroll
      for (int nj = 0; nj < 2; ++nj) {
        acc[mi][2 + nj] = MFMA16(al[mi][0], bh[nj][0], acc[mi][2 + nj]);
        acc[mi][2 + nj] = MFMA16(al[mi][1], bh[nj][1], acc[mi][2 + nj]);
      }
    SCHED0();
    // Q3: ah x bh
    #pragma unroll
    for (int mi = 0; mi < 4; ++mi)
      #pragma unroll
      for (int nj = 0; nj < 2; ++nj) {
        acc[4 + mi][2 + nj] = MFMA16(ah[mi][0], bh[nj][0], acc[4 + mi][2 + nj]);
        acc[4 + mi][2 + nj] = MFMA16(ah[mi][1], bh[nj][1], acc[4 + mi][2 + nj]);
      }
    // Q4: ah x bl
    #pragma unroll
    for (int mi = 0; mi < 4; ++mi)
      #pragma unroll
      for (int nj = 0; nj < 2; ++nj) {
        acc[4 + mi][nj] = MFMA16(ah[mi][0], bl[nj][0], acc[4 + mi][nj]);
        acc[4 + mi][nj] = MFMA16(ah[mi][1], bl[nj][1], acc[4 + mi][nj]);
      }
    __builtin_amdgcn_s_setprio(0);

    // tile t+1's staging (issued a full tile ago) must be in LDS before
    // anyone reads it next iteration
    WAITVM(0);
    BAR();
  }
  #undef STAGETILE

  // ---- epilogue: C = acc + bias (non-temporal: don't churn L3) ----
  // C/D layout: col = lane&15, row = (lane>>4)*4 + reg
  #pragma unroll
  for (int nj = 0; nj < 4; ++nj) {
    int col = (int)n0 + wn * 64 + nj * 16 + laneq;
    float bv = bias[col];
    #pragma unroll
    for (int mi = 0; mi < 8; ++mi) {
      size_t row = m0 + wm * 128 + mi * 16 + laneh * 4;
      float* cp = C + row * (size_t)N + col;
      #pragma unroll
      for (int r = 0; r < 4; ++r)
        __builtin_nontemporal_store(acc[mi][nj][r] + bv, cp + (size_t)r * N);
    }
  }
}

// ---------- launcher ----------
extern "C" void kernel_launch(void* const* d_in, const int* in_sizes, int n_in,
                              void* d_out, int out_size, void* d_ws, size_t ws_size,
                              hipStream_t stream) {
  const float* x    = (const float*)d_in[0];
  const float* w    = (const float*)d_in[1];
  const float* bias = (const float*)d_in[2];
  float* out = (float*)d_out;

  const long long xN = in_sizes[0];          // M*K
  const long long wN = in_sizes[1];          // N*K
  const int N = in_sizes[2];
  const int K = (int)(wN / N);
  const int M = (int)(xN / K);

  unsigned short* xb = (unsigned short*)d_ws;          // M*K bf16
  unsigned short* wb = xb + xN;                        // N*K bf16

  long long ngroups = xN / 128;
  long long qblocks = (ngroups + 3) / 4;
  quant_x_kernel<<<(int)qblocks, 256, 0, stream>>>(x, xb, ngroups);

  long long cblocks = (wN + 2047) / 2048;
  cvt_w_kernel<<<(int)cblocks, 256, 0, stream>>>(w, wb, wN);

  int grid = (M / BM) * (N / BN);
  gemm256_bias<<<grid, 512, 0, stream>>>(xb, wb, bias, out, M, N, K);
}